// Round 10
// baseline (73.255 us; speedup 1.0000x reference)
//
#include <hip/hip_runtime.h>
#include <hip/hip_bf16.h>

using u16 = unsigned short;
using u32 = unsigned int;

namespace {
constexpr int S   = 2048;
constexpr int HID = 1024;
constexpr int M   = 4096;                  // B*S
constexpr int K   = 1024;                  // inner dim of both big GEMMs
}

typedef __attribute__((ext_vector_type(8)))  short short8;   // 8 bf16 = 4 VGPR
typedef __attribute__((ext_vector_type(4)))  float f32x4;
typedef __attribute__((ext_vector_type(16))) float f32x16;

__device__ __forceinline__ u16 f2bf(float f) {
    u32 u = __builtin_bit_cast(u32, f);
    u += 0x7fffu + ((u >> 16) & 1u);       // RNE
    return (u16)(u >> 16);
}
__device__ __forceinline__ float bf2f(u16 h) {
    return __builtin_bit_cast(float, (u32)h << 16);
}
__device__ __forceinline__ float phi(float x) {   // elu(x)+1
    return x > 0.f ? x + 1.f : __expf(x);
}
__device__ __forceinline__ void glds16(const u16* g, u16* l) {
    __builtin_amdgcn_global_load_lds(
        (const __attribute__((address_space(1))) u32*)g,
        (__attribute__((address_space(3))) u32*)l, 16, 0, 0);
}

// ---- single-bf16 MFMA GEMM, 64x128 tile, BK=64, dbuf LDS, 32x32x16 MFMA ---
// 4 waves 2x2: wave rows wm*32..+32, cols wn*64..+64 (2x 32x32 acc tiles).
// LDS rows 64 u16 = 128 B; k-slot XOR swizzle (slot ^ row&7) store & read.
// XCD-bijective block remap (grids are multiples of 8).
// MODE 0: QKV projection; epilogue q->rope+phi->bf16 Cq, k->rope+phi*mask->f32,
//         v passthrough->f32. MODE 1: plain f32 C, z-batched.
template <int MODE>
__global__ __launch_bounds__(256, 3) void gemm_k(
    const u16* __restrict__ A, const u16* __restrict__ B,
    u16* __restrict__ Cq, float* __restrict__ Ckv,
    float* __restrict__ Cf, int ldc, int zAr, int zBr, int zCr,
    const float* __restrict__ Cos, const float* __restrict__ Sin,
    const int* __restrict__ Mask)
{
    constexpr int BK = 64;
    constexpr int NT = K / BK;                     // 16 K-tiles
    __shared__ __align__(16) u16 sA0[64 * BK],  sA1[64 * BK];    // 8 KB each
    __shared__ __align__(16) u16 sB0[128 * BK], sB1[128 * BK];   // 16 KB each

    // XCD-bijective remap (nwg % 8 == 0)
    const int gx = gridDim.x, gy = gridDim.y;
    const int nwg  = gx * gy * gridDim.z;
    const int orig = blockIdx.x + gx * (blockIdx.y + gy * blockIdx.z);
    const int wgid = (orig & 7) * (nwg >> 3) + (orig >> 3);
    const int bx = wgid % gx;
    const int rest = wgid / gx;
    const int by = rest % gy, bz = rest / gy;

    A += (size_t)bz * zAr * K;
    B += (size_t)bz * zBr * K;
    if (MODE == 1) Cf += (size_t)bz * zCr * ldc;

    const int tid  = threadIdx.x;
    const int lane = tid & 63, w = tid >> 6;
    const int wm = w & 1, wn = w >> 1;             // 2x2 wave grid
    const int m0 = bx * 64, n0 = by * 128;
    const int l31 = lane & 31, khalf = lane >> 5, l7 = lane & 7;

    const int srow  = lane >> 3;                   // 0..7 staging row in chunk
    const int sslot = lane & 7;                    // LDS k-slot this lane fills
    const int sswz  = (sslot ^ srow) * 8;          // swizzled global k-elem

    const u16* Asrc = A + (size_t)(m0 + w * 8 + srow) * K + sswz;
    const u16* Bsrc = B + (size_t)(n0 + w * 8 + srow) * K + sswz;
    const int ldsb = (w * 8) * BK;                 // wave-uniform LDS base

    f32x16 acc0 = {}, acc1 = {};
    const int arow = wm * 32 + l31;                // A row this lane consumes
    const int brow0 = wn * 64 + l31, brow1 = brow0 + 32;

#define STAGE(dA, dB, kt)                                          \
    do {                                                           \
        glds16(Asrc + (kt),                 dA + ldsb);            \
        glds16(Asrc + (size_t)32 * K + (kt), dA + 32 * BK + ldsb); \
        glds16(Bsrc + (kt),                 dB + ldsb);            \
        glds16(Bsrc + (size_t)32 * K + (kt), dB + 32 * BK + ldsb); \
        glds16(Bsrc + (size_t)64 * K + (kt), dB + 64 * BK + ldsb); \
        glds16(Bsrc + (size_t)96 * K + (kt), dB + 96 * BK + ldsb); \
    } while (0)

#define COMPUTE(sAc, sBc)                                                    \
    do {                                                                     \
        _Pragma("unroll")                                                    \
        for (int st = 0; st < 4; ++st) {                                     \
            const int slot = st * 2 + khalf;       /* global k-slot */       \
            const int ks = (slot ^ l7) * 8;        /* swizzled LDS slot */   \
            short8 a  = *(const short8*)(sAc + arow  * BK + ks);             \
            short8 b0 = *(const short8*)(sBc + brow0 * BK + ks);             \
            short8 b1 = *(const short8*)(sBc + brow1 * BK + ks);             \
            acc0 = __builtin_amdgcn_mfma_f32_32x32x16_bf16(a, b0, acc0, 0, 0, 0); \
            acc1 = __builtin_amdgcn_mfma_f32_32x32x16_bf16(a, b1, acc1, 0, 0, 0); \
        }                                                                    \
    } while (0)

#define SYNC()                                              \
    do {                                                    \
        asm volatile("s_waitcnt vmcnt(0)" ::: "memory");    \
        __syncthreads();                                    \
    } while (0)

    STAGE(sA0, sB0, 0);
    SYNC();
#pragma unroll 1
    for (int t = 0; t < NT; t += 2) {
        if (t + 1 < NT) STAGE(sA1, sB1, (t + 1) * BK);     // prefetch t+1
        COMPUTE(sA0, sB0);                                  // compute t
        SYNC();
        if (t + 2 < NT) STAGE(sA0, sB0, (t + 2) * BK);     // prefetch t+2
        COMPUTE(sA1, sB1);                                  // compute t+1
        SYNC();
    }
#undef STAGE
#undef COMPUTE
#undef SYNC

    const bool isQ = (MODE == 0) && (n0 < 1024);
    const bool isK = (MODE == 0) && (n0 >= 1024) && (n0 < 1280);
    const int colb = n0 + wn * 64 + l31;           // tile0 col; tile1 = +32
#pragma unroll
    for (int r = 0; r < 16; ++r) {
        // verified 32x32 C/D layout: col = lane&31, row = (r&3)+8*(r>>2)+4*khalf
        const int row = m0 + wm * 32 + (r & 3) + 8 * (r >> 2) + 4 * khalf;
        float v0 = acc0[r], v1 = acc1[r];          // head dims (d, d+32)
        if (MODE == 1) {
            float* cr = &Cf[(size_t)row * ldc + colb];
            cr[0] = v0; cr[32] = v1;
            continue;
        }
        if (isQ || isK) {                          // rope + phi (head-aligned)
            const int sb = (row & (S - 1)) * 64;
            float r0 = v0 * Cos[sb + l31]      - v1 * Sin[sb + l31];
            float r1 = v1 * Cos[sb + l31 + 32] + v0 * Sin[sb + l31 + 32];
            v0 = phi(r0); v1 = phi(r1);
        }
        if (isQ) {
            u16* cr = &Cq[(size_t)row * 1024 + colb];
            cr[0] = f2bf(v0); cr[32] = f2bf(v1);
        } else if (isK) {
            const float mv = (float)Mask[row];
            float* cr = &Ckv[(size_t)row * 512 + (colb - 1024)];
            cr[0] = v0 * mv; cr[32] = v1 * mv;
        } else {                                   // v passthrough
            float* cr = &Ckv[(size_t)row * 512 + 256 + (colb - 1280)];
            cr[0] = v0; cr[32] = v1;
        }
    }
}

// ---------- fused preprocessing: x->bf16 + 4 weight transposes, 1 launch ----
__global__ __launch_bounds__(256) void prep_k(
    const float* __restrict__ X,  u16* __restrict__ Xb,
    const float* __restrict__ Wq, const float* __restrict__ Wk,
    const float* __restrict__ Wv, const float* __restrict__ Wo,
    u16* __restrict__ wt, u16* __restrict__ wot)
{
    const int bid = blockIdx.x, tid = threadIdx.x;
    if (bid < 4096) {
        const int i = (bid * 256 + tid) * 4;
        float4 v = *reinterpret_cast<const float4*>(&X[i]);
        ushort4 h;
        h.x = f2bf(v.x); h.y = f2bf(v.y); h.z = f2bf(v.z); h.w = f2bf(v.w);
        *reinterpret_cast<ushort4*>(&Xb[i]) = h;
        return;
    }
    int r = bid - 4096;
    const float* W; u16* T; int N, nbase, bx, by;
    if (r < 1024)      { W = Wq; T = wt;  N = 1024; nbase = 0;    bx = r & 31; by = r >> 5; }
    else if (r < 1280) { r -= 1024; W = Wk; T = wt; N = 256; nbase = 1024; bx = r & 7; by = r >> 3; }
    else if (r < 1536) { r -= 1280; W = Wv; T = wt; N = 256; nbase = 1280; bx = r & 7; by = r >> 3; }
    else               { r -= 1536; W = Wo; T = wot; N = 1024; nbase = 0;  bx = r & 31; by = r >> 5; }

    __shared__ float t[32][33];
    const int n0 = bx * 32, k0 = by * 32;
    const int tx = tid & 31, ty = tid >> 5;        // 32 x 8
#pragma unroll
    for (int i = 0; i < 4; ++i)
        t[ty + i * 8][tx] = W[(size_t)(k0 + ty + i * 8) * N + n0 + tx];
    __syncthreads();
#pragma unroll
    for (int i = 0; i < 4; ++i) {
        const int n = ty + i * 8;
        T[(size_t)(nbase + n0 + n) * 1024 + k0 + tx] = f2bf(t[tx][n]);
    }
}

// ---------- stage1: per (group, 64-row chunk) partial KV + Ksum -------------
__global__ __launch_bounds__(256) void kv_stage1_k(
    const float* __restrict__ KVf, float* __restrict__ part)
{
    const int g  = blockIdx.x;             // b*4 + kvh
    const int ch = blockIdx.y;             // 32 chunks of 64 rows
    const int b  = g >> 2, kvh = g & 3;
    const int tid = threadIdx.x;

    __shared__ float ks[64][64];
    __shared__ float vs[64][64];
    const int m0 = b * S + ch * 64;
#pragma unroll
    for (int l = 0; l < 4; ++l) {
        int idx = tid + l * 256;           // 0..1023
        int r = idx >> 4, q4 = (idx & 15) * 4;
        const float* src = KVf + (size_t)(m0 + r) * 512 + kvh * 64;
        *reinterpret_cast<float4*>(&ks[r][q4]) = *reinterpret_cast<const float4*>(src + q4);
        *reinterpret_cast<float4*>(&vs[r][q4]) = *reinterpret_cast<const float4*>(src + 256 + q4);
    }
    __syncthreads();

    const int i = tid >> 2, j0 = (tid & 3) * 16;
    float4 a0 = {0,0,0,0}, a1 = {0,0,0,0}, a2 = {0,0,0,0}, a3 = {0,0,0,0};
#pragma unroll 8
    for (int r = 0; r < 64; ++r) {
        float kv = ks[r][i];
        float4 w0 = *reinterpret_cast<const float4*>(&vs[r][j0]);
        float4 w1 = *reinterpret_cast<const float4*>(&vs[r][j0 + 4]);
        float4 w2 = *reinterpret_cast<const float4*>(&vs[r][j0 + 8]);
        float4 w3 = *reinterpret_cast<const float4*>(&vs[r][j0 + 12]);
        a0.x = fmaf(kv, w0.x, a0.x); a0.y = fmaf(kv, w0.y, a0.y);
        a0.z = fmaf(kv, w0.z, a0.z); a0.w = fmaf(kv, w0.w, a0.w);
        a1.x = fmaf(kv, w1.x, a1.x); a1.y = fmaf(kv, w1.y, a1.y);
        a1.z = fmaf(kv, w1.z, a1.z); a1.w = fmaf(kv, w1.w, a1.w);
        a2.x = fmaf(kv, w2.x, a2.x); a2.y = fmaf(kv, w2.y, a2.y);
        a2.z = fmaf(kv, w2.z, a2.z); a2.w = fmaf(kv, w2.w, a2.w);
        a3.x = fmaf(kv, w3.x, a3.x); a3.y = fmaf(kv, w3.y, a3.y);
        a3.z = fmaf(kv, w3.z, a3.z); a3.w = fmaf(kv, w3.w, a3.w);
    }
    float* dst = part + ((size_t)g * 32 + ch) * 4160;
    float* d0 = dst + i * 64 + j0;
    *reinterpret_cast<float4*>(d0)      = a0;
    *reinterpret_cast<float4*>(d0 + 4)  = a1;
    *reinterpret_cast<float4*>(d0 + 8)  = a2;
    *reinterpret_cast<float4*>(d0 + 12) = a3;
    if (tid < 64) {
        float ksum = 0.f;
#pragma unroll 8
        for (int r = 0; r < 64; ++r) ksum += ks[r][tid];
        dst[4096 + tid] = ksum;
    }
}

// ---------- stage2: sum 32 partials; KV -> bf16, Ksum -> f32 ----------
__global__ __launch_bounds__(256) void kv_reduce_k(
    const float* __restrict__ part, u16* __restrict__ KVh,
    float* __restrict__ Ksumf)
{
    const int g = blockIdx.x;
    const int e = blockIdx.y * 256 + threadIdx.x;
    if (e >= 4160) return;
    const float* p = part + (size_t)g * 32 * 4160 + e;
    float s = 0.f;
#pragma unroll 8
    for (int c = 0; c < 32; ++c) s += p[(size_t)c * 4160];
    if (e < 4096) KVh[g * 4096 + e] = f2bf(s);
    else          Ksumf[g * 64 + (e - 4096)] = s;
}

// ---- fused: blocks 0..255 = kw_gemm (KWT), blocks 256..511 = qhat ----------
__global__ __launch_bounds__(256) void kwqhat_k(
    const u16* __restrict__ WoT, const u16* __restrict__ KVb,
    u16* __restrict__ KWT,
    const u16* __restrict__ Qt, const float* __restrict__ Ksumf,
    u16* __restrict__ Qh)
{
    const int tid = threadIdx.x;
    if (blockIdx.x >= 256) {                       // ---- qhat part ----
        const int t = (blockIdx.x - 256) * 256 + tid;   // (m, h)
        const int m = t >> 4, h = t & 15;
        const int g = (m >> 11) * 4 + (h >> 2);
        const u16* q  = Qt + (size_t)m * 1024 + h * 64;
        const float* Ks = Ksumf + g * 64;

        float qv[64];
        float den = 0.f;
#pragma unroll
        for (int c = 0; c < 8; ++c) {
            short8 v8 = *reinterpret_cast<const short8*>(q + c * 8);
#pragma unroll
            for (int j = 0; j < 8; ++j) {
                qv[c * 8 + j] = bf2f((u16)v8[j]);
                den = fmaf(qv[c * 8 + j], Ks[c * 8 + j], den);
            }
        }
        const float rd = 1.f / fmaxf(den, 1e-6f);
        u16* o = Qh + (size_t)m * 1024 + h * 64;
#pragma unroll
        for (int c = 0; c < 8; ++c) {
            short8 ov;
#pragma unroll
            for (int j = 0; j < 8; ++j) ov[j] = (short)f2bf(qv[c * 8 + j] * rd);
            *reinterpret_cast<short8*>(o + c * 8) = ov;
        }
        return;
    }
    // ---- kw part: KWT[b][o][h*64+i] = sum_j KV[i][j] * Wo[h*64+j][o] ----
    __shared__ __align__(16) u16 sA[128 * 64];
    __shared__ __align__(16) u16 sB[64 * 64];

    const int lane = tid & 63, w = tid >> 6;
    const int o0 = (blockIdx.x & 7) * 128;
    const int gh = blockIdx.x >> 3, b = gh >> 4, h = gh & 15, g = b * 4 + (h >> 2);
    const int fr = lane & 15, fq = lane >> 4;
    const int srow = lane >> 3, sslot = lane & 7;
    const int sswz = (sslot ^ srow) * 8;

#pragma unroll
    for (int c = 0; c < 4; ++c) {                      // A: 128 rows
        const int rb = w * 32 + c * 8;
        glds16(WoT + (size_t)(o0 + rb + srow) * 1024 + h * 64 + sswz, sA + rb * 64);
    }
#pragma unroll
    for (int c = 0; c < 2; ++c) {                      // B: 64 rows
        const int rb = w * 16 + c * 8;
        glds16(KVb + (size_t)g * 4096 + (rb + srow) * 64 + sswz, sB + rb * 64);
    }
    asm volatile("s_waitcnt vmcnt(0)" ::: "memory");
    __syncthreads();

    f32x4 acc[2][4] = {};
#pragma unroll
    for (int kk = 0; kk < 2; ++kk) {
        short8 a_h[2], b_h[4];
#pragma unroll
        for (int i = 0; i < 2; ++i) {
            const int row = w * 32 + i * 16 + fr;
            a_h[i] = *(const short8*)(sA + row * 64 + ((kk * 4 + fq) ^ (fr & 7)) * 8);
        }
#pragma unroll
        for (int j = 0; j < 4; ++j) {
            const int row = j * 16 + fr;
            b_h[j] = *(const short8*)(sB + row * 64 + ((kk * 4 + fq) ^ (fr & 7)) * 8);
        }
#pragma unroll
        for (int i = 0; i < 2; ++i)
#pragma unroll
            for (int j = 0; j < 4; ++j)
                acc[i][j] = __builtin_amdgcn_mfma_f32_16x16x32_bf16(
                    a_h[i], b_h[j], acc[i][j], 0, 0, 0);
    }
#pragma unroll
    for (int i = 0; i < 2; ++i)
#pragma unroll
        for (int j = 0; j < 4; ++j)
#pragma unroll
            for (int jj = 0; jj < 4; ++jj) {
                const int row = o0 + w * 32 + i * 16 + fq * 4 + jj;   // o
                const int col = j * 16 + fr;                          // i of KV
                KWT[((size_t)b * 1024 + row) * 1024 + h * 64 + col] =
                    f2bf(acc[i][j][jj]);
            }
}

extern "C" void kernel_launch(void* const* d_in, const int* in_sizes, int n_in,
                              void* d_out, int out_size, void* d_ws, size_t ws_size,
                              hipStream_t stream)
{
    const float* x    = (const float*)d_in[0];
    const float* cosp = (const float*)d_in[1];
    const float* sinp = (const float*)d_in[2];
    const int*   msk  = (const int*)d_in[3];
    const float* Wq   = (const float*)d_in[4];
    const float* Wk   = (const float*)d_in[5];
    const float* Wv   = (const float*)d_in[6];
    const float* Wo   = (const float*)d_in[7];
    float* out = (float*)d_out;

    // ---- workspace layout (~46 MB) ----
    u16* xbf  = (u16*)d_ws;                           // [4096][1024]
    u16* wt   = xbf  + (size_t)M * K;                 // [1536][1024]
    u16* wot  = wt   + (size_t)1536 * K;              // [1024][1024] Wo^T
    u16* qt   = wot  + (size_t)K * K;                 // [4096][1024] q~ bf16
    u16* qhat = qt   + (size_t)M * K;                 // [4096][1024]
    u16* kvb  = qhat + (size_t)M * K;                 // [8][4096]
    u16* kwt  = kvb  + 8 * 4096;                      // [2][1024][1024]
    float* kvf   = (float*)(kwt + (size_t)2 * K * K); // [4096][512] k~|v f32
    float* part  = kvf + (size_t)M * 512;             // [8][32][4160]
    float* ksumf = part + (size_t)8 * 32 * 4160;      // [8][64]

    // 1) fused casts/transposes (one launch)
    prep_k<<<4096 + 1024 + 256 + 256 + 1024, 256, 0, stream>>>(
        x, xbf, Wq, Wk, Wv, Wo, wt, wot);

    // 2) QKV projection + fused rope/phi/mask epilogue (q->bf16, k|v->f32)
    gemm_k<0><<<dim3(M / 64, 1536 / 128, 1), 256, 0, stream>>>(
        xbf, wt, qt, kvf, nullptr, 0, 0, 0, 0, cosp, sinp, msk);

    // 3) KV & Ksum (atomic-free two-stage)
    kv_stage1_k<<<dim3(8, 32), 256, 0, stream>>>(kvf, part);
    kv_reduce_k<<<dim3(8, 17), 256, 0, stream>>>(part, kvb, ksumf);

    // 4) fused: KWT (per-head KV @ Wo slices) + q_hat = q~/den
    kwqhat_k<<<512, 256, 0, stream>>>(wot, kvb, kwt, qt, ksumf, qhat);

    // 5) out_b = q_hat_b @ KWT_b^T
    gemm_k<1><<<dim3(2048 / 64, HID / 128, 2), 256, 0, stream>>>(
        qhat, kwt, nullptr, nullptr, out, HID, 2048, 1024, 2048,
        nullptr, nullptr, nullptr);
}

// Round 11
// 70.216 us; speedup vs baseline: 1.0433x; 1.0433x over previous
//
#include <hip/hip_runtime.h>
#include <hip/hip_bf16.h>

using u16 = unsigned short;
using u32 = unsigned int;

namespace {
constexpr int S   = 2048;
constexpr int HID = 1024;
constexpr int M   = 4096;                  // B*S
constexpr int K   = 1024;                  // inner dim of both big GEMMs
}

typedef __attribute__((ext_vector_type(8))) short short8;   // 8 bf16 = 4 VGPR
typedef __attribute__((ext_vector_type(4))) float f32x4;

__device__ __forceinline__ u16 f2bf(float f) {
    u32 u = __builtin_bit_cast(u32, f);
    u += 0x7fffu + ((u >> 16) & 1u);       // RNE
    return (u16)(u >> 16);
}
__device__ __forceinline__ float bf2f(u16 h) {
    return __builtin_bit_cast(float, (u32)h << 16);
}
__device__ __forceinline__ float phi(float x) {   // elu(x)+1
    return x > 0.f ? x + 1.f : __expf(x);
}
__device__ __forceinline__ void glds16(const u16* g, u16* l) {
    __builtin_amdgcn_global_load_lds(
        (const __attribute__((address_space(1))) u32*)g,
        (__attribute__((address_space(3))) u32*)l, 16, 0, 0);
}

// ---- single-bf16 MFMA GEMM, 64x128, BK=64, 16x16x32 (round-9 engine) ------
// NEW: depth-2 counted-vmcnt pipeline (T4): prologue stages tiles 0,1;
// per phase: vmcnt(6) [oldest tile done] -> raw s_barrier -> COMPUTE ->
// lgkmcnt(0) -> raw s_barrier -> STAGE tile t+2. Next tile's loads stay in
// flight across compute (the __syncthreads/vmcnt(0) drain is what we remove).
// MODE 0: QKV projection; q->rope+phi->bf16, k->rope+phi*mask->f32, v->f32.
// MODE 1: plain f32 C, z-batched via zAr/zBr/zCr.
template <int MODE>
__global__ __launch_bounds__(256, 3) void gemm_k(
    const u16* __restrict__ A, const u16* __restrict__ B,
    u16* __restrict__ Cq, float* __restrict__ Ckv,
    float* __restrict__ Cf, int ldc, int zAr, int zBr, int zCr,
    const float* __restrict__ Cos, const float* __restrict__ Sin,
    const int* __restrict__ Mask)
{
    constexpr int BK = 64;
    constexpr int NT = K / BK;                     // 16 K-tiles
    __shared__ __align__(16) u16 sA0[64 * BK],  sA1[64 * BK];    // 8 KB each
    __shared__ __align__(16) u16 sB0[128 * BK], sB1[128 * BK];   // 16 KB each

    A += (size_t)blockIdx.z * zAr * K;
    B += (size_t)blockIdx.z * zBr * K;
    if (MODE == 1) Cf += (size_t)blockIdx.z * zCr * ldc;

    const int tid  = threadIdx.x;
    const int lane = tid & 63, w = tid >> 6;
    const int wm = w & 1, wn = w >> 1;             // 2x2 wave grid
    const int m0 = blockIdx.x * 64, n0 = blockIdx.y * 128;
    const int fr = lane & 15, fq = lane >> 4;

    const int srow  = lane >> 3;                   // 0..7 staging row in chunk
    const int sslot = lane & 7;                    // LDS k-slot this lane fills
    const int sswz  = (sslot ^ srow) * 8;          // swizzled global k-elem

    const u16* Asrc = A + (size_t)(m0 + w * 8 + srow) * K + sswz;
    const u16* Bsrc = B + (size_t)(n0 + w * 8 + srow) * K + sswz;
    const int ldsb = (w * 8) * BK;                 // wave-uniform LDS base

    f32x4 acc[2][4] = {};

#define STAGE(dA, dB, kt)                                          \
    do {                                                           \
        glds16(Asrc + (kt),                 dA + ldsb);            \
        glds16(Asrc + (size_t)32 * K + (kt), dA + 32 * BK + ldsb); \
        glds16(Bsrc + (kt),                 dB + ldsb);            \
        glds16(Bsrc + (size_t)32 * K + (kt), dB + 32 * BK + ldsb); \
        glds16(Bsrc + (size_t)64 * K + (kt), dB + 64 * BK + ldsb); \
        glds16(Bsrc + (size_t)96 * K + (kt), dB + 96 * BK + ldsb); \
    } while (0)

#define COMPUTE(sAc, sBc)                                                    \
    do {                                                                     \
        _Pragma("unroll")                                                    \
        for (int kk = 0; kk < 2; ++kk) {                                     \
            const int ks = ((kk * 4 + fq) ^ (fr & 7)) * 8;                   \
            short8 ah[2], bh[4];                                             \
            _Pragma("unroll")                                                \
            for (int i = 0; i < 2; ++i)                                      \
                ah[i] = *(const short8*)(sAc + (wm * 32 + i * 16 + fr) * BK + ks); \
            _Pragma("unroll")                                                \
            for (int j = 0; j < 4; ++j)                                      \
                bh[j] = *(const short8*)(sBc + (wn * 64 + j * 16 + fr) * BK + ks); \
            _Pragma("unroll")                                                \
            for (int i = 0; i < 2; ++i)                                      \
                _Pragma("unroll")                                            \
                for (int j = 0; j < 4; ++j)                                  \
                    acc[i][j] = __builtin_amdgcn_mfma_f32_16x16x32_bf16(     \
                        ah[i], bh[j], acc[i][j], 0, 0, 0);                   \
        }                                                                    \
    } while (0)

    STAGE(sA0, sB0, 0);                            // tiles 0,1 in flight (12)
    STAGE(sA1, sB1, BK);
#pragma unroll 1
    for (int t = 0; t < NT; t += 2) {
        // ---- tile t (buf0); in flight: {t, t+1} = 12 loads ----
        asm volatile("s_waitcnt vmcnt(6)" ::: "memory");   // tile t landed
        __builtin_amdgcn_s_barrier();
        COMPUTE(sA0, sB0);
        asm volatile("s_waitcnt lgkmcnt(0)" ::: "memory"); // buf0 reads done
        __builtin_amdgcn_s_barrier();
        if (t + 2 < NT) STAGE(sA0, sB0, (t + 2) * BK);     // refill buf0

        // ---- tile t+1 (buf1); in flight: {t+1, t+2?} ----
        if (t + 2 < NT) asm volatile("s_waitcnt vmcnt(6)" ::: "memory");
        else            asm volatile("s_waitcnt vmcnt(0)" ::: "memory");
        __builtin_amdgcn_s_barrier();
        COMPUTE(sA1, sB1);
        asm volatile("s_waitcnt lgkmcnt(0)" ::: "memory");
        __builtin_amdgcn_s_barrier();
        if (t + 3 < NT) STAGE(sA1, sB1, (t + 3) * BK);     // refill buf1
    }
#undef STAGE
#undef COMPUTE

    const bool isQ = (MODE == 0) && (n0 < 1024);
    const bool isK = (MODE == 0) && (n0 >= 1024) && (n0 < 1280);
#pragma unroll
    for (int i = 0; i < 2; ++i)
#pragma unroll
        for (int jj = 0; jj < 4; ++jj) {
            const int row = m0 + wm * 32 + i * 16 + fq * 4 + jj;
            float v0 = acc[i][0][jj], v1 = acc[i][1][jj];
            float v2 = acc[i][2][jj], v3 = acc[i][3][jj];
            if (MODE == 1) {
                float* cr = &Cf[(size_t)row * ldc + n0 + wn * 64 + fr];
                cr[0] = v0; cr[16] = v1; cr[32] = v2; cr[48] = v3;
                continue;
            }
            if (isQ || isK) {                      // rope + phi (head-aligned)
                const int sb = (row & (S - 1)) * 64;
                // pairs (d, d+32): (v0@fr, v2@fr+32), (v1@16+fr, v3@48+fr)
                float r0 = v0 * Cos[sb + fr]      - v2 * Sin[sb + fr];
                float r2 = v2 * Cos[sb + fr + 32] + v0 * Sin[sb + fr + 32];
                float r1 = v1 * Cos[sb + fr + 16] - v3 * Sin[sb + fr + 16];
                float r3 = v3 * Cos[sb + fr + 48] + v1 * Sin[sb + fr + 48];
                v0 = phi(r0); v1 = phi(r1); v2 = phi(r2); v3 = phi(r3);
            }
            if (isQ) {
                u16* cr = &Cq[(size_t)row * 1024 + n0 + wn * 64 + fr];
                cr[0]  = f2bf(v0); cr[16] = f2bf(v1);
                cr[32] = f2bf(v2); cr[48] = f2bf(v3);
            } else if (isK) {
                const float mv = (float)Mask[row];
                float* cr = &Ckv[(size_t)row * 512 + (n0 - 1024) + wn * 64 + fr];
                cr[0] = v0 * mv; cr[16] = v1 * mv;
                cr[32] = v2 * mv; cr[48] = v3 * mv;
            } else {                               // v passthrough
                float* cr = &Ckv[(size_t)row * 512 + 256 + (n0 - 1280) + wn * 64 + fr];
                cr[0] = v0; cr[16] = v1; cr[32] = v2; cr[48] = v3;
            }
        }
}

// ---------- fused preprocessing: x->bf16 + 4 weight transposes, 1 launch ----
__global__ __launch_bounds__(256) void prep_k(
    const float* __restrict__ X,  u16* __restrict__ Xb,
    const float* __restrict__ Wq, const float* __restrict__ Wk,
    const float* __restrict__ Wv, const float* __restrict__ Wo,
    u16* __restrict__ wt, u16* __restrict__ wot)
{
    const int bid = blockIdx.x, tid = threadIdx.x;
    if (bid < 4096) {
        const int i = (bid * 256 + tid) * 4;
        float4 v = *reinterpret_cast<const float4*>(&X[i]);
        ushort4 h;
        h.x = f2bf(v.x); h.y = f2bf(v.y); h.z = f2bf(v.z); h.w = f2bf(v.w);
        *reinterpret_cast<ushort4*>(&Xb[i]) = h;
        return;
    }
    int r = bid - 4096;
    const float* W; u16* T; int N, nbase, bx, by;
    if (r < 1024)      { W = Wq; T = wt;  N = 1024; nbase = 0;    bx = r & 31; by = r >> 5; }
    else if (r < 1280) { r -= 1024; W = Wk; T = wt; N = 256; nbase = 1024; bx = r & 7; by = r >> 3; }
    else if (r < 1536) { r -= 1280; W = Wv; T = wt; N = 256; nbase = 1280; bx = r & 7; by = r >> 3; }
    else               { r -= 1536; W = Wo; T = wot; N = 1024; nbase = 0;  bx = r & 31; by = r >> 5; }

    __shared__ float t[32][33];
    const int n0 = bx * 32, k0 = by * 32;
    const int tx = tid & 31, ty = tid >> 5;        // 32 x 8
#pragma unroll
    for (int i = 0; i < 4; ++i)
        t[ty + i * 8][tx] = W[(size_t)(k0 + ty + i * 8) * N + n0 + tx];
    __syncthreads();
#pragma unroll
    for (int i = 0; i < 4; ++i) {
        const int n = ty + i * 8;
        T[(size_t)(nbase + n0 + n) * 1024 + k0 + tx] = f2bf(t[tx][n]);
    }
}

// ---------- stage1: per (group, 64-row chunk) partial KV + Ksum -------------
__global__ __launch_bounds__(256) void kv_stage1_k(
    const float* __restrict__ KVf, float* __restrict__ part)
{
    const int g  = blockIdx.x;             // b*4 + kvh
    const int ch = blockIdx.y;             // 32 chunks of 64 rows
    const int b  = g >> 2, kvh = g & 3;
    const int tid = threadIdx.x;

    __shared__ float ks[64][64];
    __shared__ float vs[64][64];
    const int m0 = b * S + ch * 64;
#pragma unroll
    for (int l = 0; l < 4; ++l) {
        int idx = tid + l * 256;           // 0..1023
        int r = idx >> 4, q4 = (idx & 15) * 4;
        const float* src = KVf + (size_t)(m0 + r) * 512 + kvh * 64;
        *reinterpret_cast<float4*>(&ks[r][q4]) = *reinterpret_cast<const float4*>(src + q4);
        *reinterpret_cast<float4*>(&vs[r][q4]) = *reinterpret_cast<const float4*>(src + 256 + q4);
    }
    __syncthreads();

    const int i = tid >> 2, j0 = (tid & 3) * 16;
    float4 a0 = {0,0,0,0}, a1 = {0,0,0,0}, a2 = {0,0,0,0}, a3 = {0,0,0,0};
#pragma unroll 8
    for (int r = 0; r < 64; ++r) {
        float kv = ks[r][i];
        float4 w0 = *reinterpret_cast<const float4*>(&vs[r][j0]);
        float4 w1 = *reinterpret_cast<const float4*>(&vs[r][j0 + 4]);
        float4 w2 = *reinterpret_cast<const float4*>(&vs[r][j0 + 8]);
        float4 w3 = *reinterpret_cast<const float4*>(&vs[r][j0 + 12]);
        a0.x = fmaf(kv, w0.x, a0.x); a0.y = fmaf(kv, w0.y, a0.y);
        a0.z = fmaf(kv, w0.z, a0.z); a0.w = fmaf(kv, w0.w, a0.w);
        a1.x = fmaf(kv, w1.x, a1.x); a1.y = fmaf(kv, w1.y, a1.y);
        a1.z = fmaf(kv, w1.z, a1.z); a1.w = fmaf(kv, w1.w, a1.w);
        a2.x = fmaf(kv, w2.x, a2.x); a2.y = fmaf(kv, w2.y, a2.y);
        a2.z = fmaf(kv, w2.z, a2.z); a2.w = fmaf(kv, w2.w, a2.w);
        a3.x = fmaf(kv, w3.x, a3.x); a3.y = fmaf(kv, w3.y, a3.y);
        a3.z = fmaf(kv, w3.z, a3.z); a3.w = fmaf(kv, w3.w, a3.w);
    }
    float* dst = part + ((size_t)g * 32 + ch) * 4160;
    float* d0 = dst + i * 64 + j0;
    *reinterpret_cast<float4*>(d0)      = a0;
    *reinterpret_cast<float4*>(d0 + 4)  = a1;
    *reinterpret_cast<float4*>(d0 + 8)  = a2;
    *reinterpret_cast<float4*>(d0 + 12) = a3;
    if (tid < 64) {
        float ksum = 0.f;
#pragma unroll 8
        for (int r = 0; r < 64; ++r) ksum += ks[r][tid];
        dst[4096 + tid] = ksum;
    }
}

// ---------- stage2: sum 32 partials; KV -> bf16, Ksum -> f32 ----------
__global__ __launch_bounds__(256) void kv_reduce_k(
    const float* __restrict__ part, u16* __restrict__ KVh,
    float* __restrict__ Ksumf)
{
    const int g = blockIdx.x;
    const int e = blockIdx.y * 256 + threadIdx.x;
    if (e >= 4160) return;
    const float* p = part + (size_t)g * 32 * 4160 + e;
    float s = 0.f;
#pragma unroll 8
    for (int c = 0; c < 32; ++c) s += p[(size_t)c * 4160];
    if (e < 4096) KVh[g * 4096 + e] = f2bf(s);
    else          Ksumf[g * 64 + (e - 4096)] = s;
}

// ---- fused: blocks 0..255 = kw_gemm (KWT), blocks 256..511 = qhat ----------
__global__ __launch_bounds__(256) void kwqhat_k(
    const u16* __restrict__ WoT, const u16* __restrict__ KVb,
    u16* __restrict__ KWT,
    const u16* __restrict__ Qt, const float* __restrict__ Ksumf,
    u16* __restrict__ Qh)
{
    const int tid = threadIdx.x;
    if (blockIdx.x >= 256) {                       // ---- qhat part ----
        const int t = (blockIdx.x - 256) * 256 + tid;   // (m, h)
        const int m = t >> 4, h = t & 15;
        const int g = (m >> 11) * 4 + (h >> 2);
        const u16* q  = Qt + (size_t)m * 1024 + h * 64;
        const float* Ks = Ksumf + g * 64;

        float qv[64];
        float den = 0.f;
#pragma unroll
        for (int c = 0; c < 8; ++c) {
            short8 v8 = *reinterpret_cast<const short8*>(q + c * 8);
#pragma unroll
            for (int j = 0; j < 8; ++j) {
                qv[c * 8 + j] = bf2f((u16)v8[j]);
                den = fmaf(qv[c * 8 + j], Ks[c * 8 + j], den);
            }
        }
        const float rd = 1.f / fmaxf(den, 1e-6f);
        u16* o = Qh + (size_t)m * 1024 + h * 64;
#pragma unroll
        for (int c = 0; c < 8; ++c) {
            short8 ov;
#pragma unroll
            for (int j = 0; j < 8; ++j) ov[j] = (short)f2bf(qv[c * 8 + j] * rd);
            *reinterpret_cast<short8*>(o + c * 8) = ov;
        }
        return;
    }
    // ---- kw part: KWT[b][o][h*64+i] = sum_j KV[i][j] * Wo[h*64+j][o] ----
    __shared__ __align__(16) u16 sA[128 * 64];
    __shared__ __align__(16) u16 sB[64 * 64];

    const int lane = tid & 63, w = tid >> 6;
    const int o0 = (blockIdx.x & 7) * 128;
    const int gh = blockIdx.x >> 3, b = gh >> 4, h = gh & 15, g = b * 4 + (h >> 2);
    const int fr = lane & 15, fq = lane >> 4;
    const int srow = lane >> 3, sslot = lane & 7;
    const int sswz = (sslot ^ srow) * 8;

#pragma unroll
    for (int c = 0; c < 4; ++c) {                      // A: 128 rows
        const int rb = w * 32 + c * 8;
        glds16(WoT + (size_t)(o0 + rb + srow) * 1024 + h * 64 + sswz, sA + rb * 64);
    }
#pragma unroll
    for (int c = 0; c < 2; ++c) {                      // B: 64 rows
        const int rb = w * 16 + c * 8;
        glds16(KVb + (size_t)g * 4096 + (rb + srow) * 64 + sswz, sB + rb * 64);
    }
    asm volatile("s_waitcnt vmcnt(0)" ::: "memory");
    __syncthreads();

    f32x4 acc[2][4] = {};
#pragma unroll
    for (int kk = 0; kk < 2; ++kk) {
        short8 a_h[2], b_h[4];
#pragma unroll
        for (int i = 0; i < 2; ++i) {
            const int row = w * 32 + i * 16 + fr;
            a_h[i] = *(const short8*)(sA + row * 64 + ((kk * 4 + fq) ^ (fr & 7)) * 8);
        }
#pragma unroll
        for (int j = 0; j < 4; ++j) {
            const int row = j * 16 + fr;
            b_h[j] = *(const short8*)(sB + row * 64 + ((kk * 4 + fq) ^ (fr & 7)) * 8);
        }
#pragma unroll
        for (int i = 0; i < 2; ++i)
#pragma unroll
            for (int j = 0; j < 4; ++j)
                acc[i][j] = __builtin_amdgcn_mfma_f32_16x16x32_bf16(
                    a_h[i], b_h[j], acc[i][j], 0, 0, 0);
    }
#pragma unroll
    for (int i = 0; i < 2; ++i)
#pragma unroll
        for (int j = 0; j < 4; ++j)
#pragma unroll
            for (int jj = 0; jj < 4; ++jj) {
                const int row = o0 + w * 32 + i * 16 + fq * 4 + jj;   // o
                const int col = j * 16 + fr;                          // i of KV
                KWT[((size_t)b * 1024 + row) * 1024 + h * 64 + col] =
                    f2bf(acc[i][j][jj]);
            }
}

extern "C" void kernel_launch(void* const* d_in, const int* in_sizes, int n_in,
                              void* d_out, int out_size, void* d_ws, size_t ws_size,
                              hipStream_t stream)
{
    const float* x    = (const float*)d_in[0];
    const float* cosp = (const float*)d_in[1];
    const float* sinp = (const float*)d_in[2];
    const int*   msk  = (const int*)d_in[3];
    const float* Wq   = (const float*)d_in[4];
    const float* Wk   = (const float*)d_in[5];
    const float* Wv   = (const float*)d_in[6];
    const float* Wo   = (const float*)d_in[7];
    float* out = (float*)d_out;

    // ---- workspace layout (~46 MB) ----
    u16* xbf  = (u16*)d_ws;                           // [4096][1024]
    u16* wt   = xbf  + (size_t)M * K;                 // [1536][1024]
    u16* wot  = wt   + (size_t)1536 * K;              // [1024][1024] Wo^T
    u16* qt   = wot  + (size_t)K * K;                 // [4096][1024] q~ bf16
    u16* qhat = qt   + (size_t)M * K;                 // [4096][1024]
    u16* kvb  = qhat + (size_t)M * K;                 // [8][4096]
    u16* kwt  = kvb  + 8 * 4096;                      // [2][1024][1024]
    float* kvf   = (float*)(kwt + (size_t)2 * K * K); // [4096][512] k~|v f32
    float* part  = kvf + (size_t)M * 512;             // [8][32][4160]
    float* ksumf = part + (size_t)8 * 32 * 4160;      // [8][64]

    // 1) fused casts/transposes (one launch)
    prep_k<<<4096 + 1024 + 256 + 256 + 1024, 256, 0, stream>>>(
        x, xbf, Wq, Wk, Wv, Wo, wt, wot);

    // 2) QKV projection + fused rope/phi/mask epilogue (q->bf16, k|v->f32)
    gemm_k<0><<<dim3(M / 64, 1536 / 128, 1), 256, 0, stream>>>(
        xbf, wt, qt, kvf, nullptr, 0, 0, 0, 0, cosp, sinp, msk);

    // 3) KV & Ksum (atomic-free two-stage)
    kv_stage1_k<<<dim3(8, 32), 256, 0, stream>>>(kvf, part);
    kv_reduce_k<<<dim3(8, 17), 256, 0, stream>>>(part, kvb, ksumf);

    // 4) fused: KWT (per-head KV @ Wo slices) + q_hat = q~/den
    kwqhat_k<<<512, 256, 0, stream>>>(wot, kvb, kwt, qt, ksumf, qhat);

    // 5) out_b = q_hat_b @ KWT_b^T
    gemm_k<1><<<dim3(2048 / 64, HID / 128, 2), 256, 0, stream>>>(
        qhat, kwt, nullptr, nullptr, out, HID, 2048, 1024, 2048,
        nullptr, nullptr, nullptr);
}